// Round 2
// baseline (20736.884 us; speedup 1.0000x reference)
//
#include <hip/hip_runtime.h>
#include <cstdint>
#include <cstddef>

#define LRELU(v) ((v) > 0.f ? (v) : 0.2f * (v))

// ---------------------------------------------------------------- conv 4x4 s2 p1
__global__ void conv_down_k(const float* __restrict__ in, const float* __restrict__ w,
                            float* __restrict__ out,
                            int B, int Cin, int Hin, int Win, int Cout) {
    int Ho = Hin >> 1, Wo = Win >> 1;
    int cout = blockIdx.y;
    int b = blockIdx.z;
    extern __shared__ float sw[];
    int nw = Cin * 16;
    int tid = threadIdx.y * blockDim.x + threadIdx.x;
    int nth = blockDim.x * blockDim.y;
    for (int i = tid; i < nw; i += nth) sw[i] = w[(size_t)cout * nw + i];
    __syncthreads();
    int tilesW = (Wo + blockDim.x - 1) / blockDim.x;
    int tw = blockIdx.x % tilesW, th = blockIdx.x / tilesW;
    int wo = tw * blockDim.x + threadIdx.x;
    int ho = th * blockDim.y + threadIdx.y;
    if (wo >= Wo || ho >= Ho) return;
    int hi0 = 2 * ho - 1, wi0 = 2 * wo - 1;
    const float* inb = in + (size_t)b * Cin * Hin * Win;
    float acc = 0.f;
    for (int ci = 0; ci < Cin; ++ci) {
        const float* ip = inb + (size_t)ci * Hin * Win;
        const float* wp = sw + ci * 16;
#pragma unroll
        for (int r = 0; r < 4; ++r) {
            int hi = hi0 + r;
            if ((unsigned)hi >= (unsigned)Hin) continue;
            const float* row = ip + (size_t)hi * Win;
#pragma unroll
            for (int s = 0; s < 4; ++s) {
                int wi = wi0 + s;
                if ((unsigned)wi < (unsigned)Win) acc = fmaf(row[wi], wp[r * 4 + s], acc);
            }
        }
    }
    out[(((size_t)b * Cout + cout) * Ho + ho) * Wo + wo] = acc;
}

// ---------------------------------------------------------------- conv 3x3 s1 p1 (2-way channel concat input)
__global__ void conv3_k(const float* __restrict__ inA, int CinA,
                        const float* __restrict__ inB, int CinB,
                        const float* __restrict__ w,
                        float* __restrict__ out,
                        int B, int H, int W, int Cout) {
    int cout = blockIdx.y, b = blockIdx.z;
    int Cin = CinA + CinB;
    extern __shared__ float sw[];
    int nw = Cin * 9;
    int tid = threadIdx.y * blockDim.x + threadIdx.x;
    int nth = blockDim.x * blockDim.y;
    for (int i = tid; i < nw; i += nth) sw[i] = w[(size_t)cout * nw + i];
    __syncthreads();
    int tilesW = (W + blockDim.x - 1) / blockDim.x;
    int tw = blockIdx.x % tilesW, th = blockIdx.x / tilesW;
    int x = tw * blockDim.x + threadIdx.x;
    int y = th * blockDim.y + threadIdx.y;
    if (x >= W || y >= H) return;
    float acc = 0.f;
    for (int half = 0; half < 2; ++half) {
        const float* src = half ? inB : inA;
        int C0 = half ? CinB : CinA;
        int cofs = half ? CinA : 0;
        if (!src || C0 == 0) continue;
        const float* inb = src + (size_t)b * C0 * H * W;
        for (int ci = 0; ci < C0; ++ci) {
            const float* ip = inb + (size_t)ci * H * W;
            const float* wp = sw + (size_t)(cofs + ci) * 9;
#pragma unroll
            for (int r = 0; r < 3; ++r) {
                int yy = y + r - 1;
                if ((unsigned)yy >= (unsigned)H) continue;
                const float* row = ip + (size_t)yy * W;
#pragma unroll
                for (int s = 0; s < 3; ++s) {
                    int xx = x + s - 1;
                    if ((unsigned)xx < (unsigned)W) acc = fmaf(row[xx], wp[r * 3 + s], acc);
                }
            }
        }
    }
    out[(((size_t)b * Cout + cout) * H + y) * W + x] = acc;
}

// ---------------------------------------------------------------- BN stats: per-channel mean & rsqrt(var+eps)
__global__ void bn_stats_k(const float* __restrict__ z, float* __restrict__ stats,
                           int B, int C, int HW) {
    int c = blockIdx.x;
    float s = 0.f, s2 = 0.f;
    for (int b = 0; b < B; ++b) {
        const float* p = z + ((size_t)b * C + c) * HW;
        for (int i = threadIdx.x; i < HW; i += blockDim.x) {
            float v = p[i];
            s += v;
            s2 = fmaf(v, v, s2);
        }
    }
    __shared__ float sb1[16], sb2[16];
    for (int off = 32; off; off >>= 1) {
        s += __shfl_down(s, off, 64);
        s2 += __shfl_down(s2, off, 64);
    }
    int wid = threadIdx.x >> 6, lane = threadIdx.x & 63;
    if (lane == 0) { sb1[wid] = s; sb2[wid] = s2; }
    __syncthreads();
    if (threadIdx.x == 0) {
        int nwv = blockDim.x >> 6;
        s = 0.f; s2 = 0.f;
        for (int i = 0; i < nwv; ++i) { s += sb1[i]; s2 += sb2[i]; }
        float n = (float)B * (float)HW;
        float m = s / n;
        float var = s2 / n - m * m;
        stats[c] = m;
        stats[C + c] = rsqrtf(var + 1e-5f);
    }
}

// ---------------------------------------------------------------- BN apply + LReLU (in place)
__global__ void bn_act_k(float* __restrict__ z, const float* __restrict__ stats,
                         int C, int HW, size_t total) {
    size_t stride = (size_t)gridDim.x * blockDim.x;
    for (size_t i = (size_t)blockIdx.x * blockDim.x + threadIdx.x; i < total; i += stride) {
        int c = (int)((i / (size_t)HW) % (size_t)C);
        float v = (z[i] - stats[c]) * stats[C + c];
        z[i] = LRELU(v);
    }
}

// ---------------------------------------------------------------- logit conv: (B,Cin,8,8) -> 5x5 valid 4x4
__global__ void logit_k(const float* __restrict__ in, const float* __restrict__ w,
                        float* __restrict__ outp, int Cin, int outStrideB, int chOfs) {
    int p = blockIdx.x, b = blockIdx.y;
    int oy = p / 5, ox = p % 5;
    const float* inb = in + (size_t)b * Cin * 64;
    float acc = 0.f;
    int n = Cin * 16;
    for (int idx = threadIdx.x; idx < n; idx += blockDim.x) {
        int c = idx >> 4, t = idx & 15, r = t >> 2, s = t & 3;
        acc = fmaf(inb[(size_t)c * 64 + (oy + r) * 8 + (ox + s)], w[idx], acc);
    }
    __shared__ float sb[4];
    for (int off = 32; off; off >>= 1) acc += __shfl_down(acc, off, 64);
    int wid = threadIdx.x >> 6, lane = threadIdx.x & 63;
    if (lane == 0) sb[wid] = acc;
    __syncthreads();
    if (threadIdx.x == 0) {
        float t = sb[0] + sb[1] + sb[2] + sb[3];
        outp[(size_t)b * outStrideB + chOfs + p] = t;
    }
}

// ---------------------------------------------------------------- final conv: pooled (B,128,8,8) -> 5x5 valid
__global__ void final_k(const float* __restrict__ ssum, const float* __restrict__ cnt,
                        const float* __restrict__ w, float* __restrict__ outp) {
    int p = blockIdx.x, b = blockIdx.y;
    int oy = p / 5, ox = p % 5;
    float inv = 1.f / fmaxf(cnt[b], 1.f);
    const float* inb = ssum + (size_t)b * 128 * 64;
    float acc = 0.f;
    for (int idx = threadIdx.x; idx < 128 * 16; idx += blockDim.x) {
        int c = idx >> 4, t = idx & 15, r = t >> 2, s = t & 3;
        acc = fmaf(inb[(size_t)c * 64 + (oy + r) * 8 + (ox + s)], w[idx], acc);
    }
    __shared__ float sb[4];
    for (int off = 32; off; off >>= 1) acc += __shfl_down(acc, off, 64);
    int wid = threadIdx.x >> 6, lane = threadIdx.x & 63;
    if (lane == 0) sb[wid] = acc;
    __syncthreads();
    if (threadIdx.x == 0) {
        float t = sb[0] + sb[1] + sb[2] + sb[3];
        outp[(size_t)b * 25 + p] = t * inv;
    }
}

// ---------------------------------------------------------------- ROI align (out=8, n=2) fused with segment-sum
__global__ void roi_pool_k(const float* __restrict__ feat, const float* __restrict__ boxes,
                           int C, int H, int W,
                           float* __restrict__ ssum, float* __restrict__ cnt) {
    int k = blockIdx.x;
    const float* bx = boxes + (size_t)k * 5;
    __shared__ int sx0[16], sx1[16], sy0[16], sy1[16];
    __shared__ float slx[16], sly[16];
    __shared__ int sbid;
    int tid = threadIdx.x;
    if (tid < 16) {
        float x1 = bx[1], y1 = bx[2], x2 = bx[3], y2 = bx[4];
        float rw = fmaxf(x2 - x1, 1.0f), rh = fmaxf(y2 - y1, 1.0f);
        float g = ((float)tid + 0.5f) * 0.5f;
        float xs = fminf(fmaxf(x1 + g * (rw * 0.125f), 0.f), (float)(W - 1));
        float ys = fminf(fmaxf(y1 + g * (rh * 0.125f), 0.f), (float)(H - 1));
        int x0 = (int)floorf(xs), y0 = (int)floorf(ys);
        sx0[tid] = x0; sy0[tid] = y0;
        sx1[tid] = min(x0 + 1, W - 1);
        sy1[tid] = min(y0 + 1, H - 1);
        slx[tid] = xs - (float)x0;
        sly[tid] = ys - (float)y0;
        if (tid == 0) sbid = (int)bx[0];
    }
    __syncthreads();
    int bid = sbid;
    const float* fb = feat + (size_t)bid * C * H * W;
    int n = C * 64;
    for (int idx = tid; idx < n; idx += blockDim.x) {
        int c = idx >> 6, p = idx & 63, oy = p >> 3, ox = p & 7;
        const float* fc = fb + (size_t)c * H * W;
        float acc = 0.f;
#pragma unroll
        for (int iy = 0; iy < 2; ++iy) {
            int gy = oy * 2 + iy;
            int y0 = sy0[gy], y1 = sy1[gy];
            float ly = sly[gy];
#pragma unroll
            for (int ix = 0; ix < 2; ++ix) {
                int gx = ox * 2 + ix;
                int x0 = sx0[gx], x1 = sx1[gx];
                float lx = slx[gx];
                float v00 = fc[y0 * W + x0], v01 = fc[y0 * W + x1];
                float v10 = fc[y1 * W + x0], v11 = fc[y1 * W + x1];
                acc += (1.f - ly) * ((1.f - lx) * v00 + lx * v01) + ly * ((1.f - lx) * v10 + lx * v11);
            }
        }
        atomicAdd(&ssum[((size_t)bid * C + c) * 64 + p], acc * 0.25f);
    }
    if (tid == 0) atomicAdd(&cnt[bid], 1.0f);
}

// ---------------------------------------------------------------- host-side launch helpers
static void launch_down(const float* in, const float* w, float* out,
                        int B, int Cin, int Hin, int Win, int Cout, hipStream_t s) {
    int Ho = Hin / 2, Wo = Win / 2;
    int TW = Wo < 32 ? Wo : 32;
    int TH = 256 / TW; if (TH > Ho) TH = Ho;
    dim3 blk(TW, TH);
    int tiles = ((Wo + TW - 1) / TW) * ((Ho + TH - 1) / TH);
    dim3 grd(tiles, Cout, B);
    size_t shm = (size_t)Cin * 16 * sizeof(float);
    hipLaunchKernelGGL(conv_down_k, grd, blk, shm, s, in, w, out, B, Cin, Hin, Win, Cout);
}

static void launch_conv3(const float* inA, int CinA, const float* inB, int CinB,
                         const float* w, float* out,
                         int B, int H, int W, int Cout, hipStream_t s) {
    int TW = W < 64 ? W : 64;
    int TH = 256 / TW; if (TH > H) TH = H;
    dim3 blk(TW, TH);
    int tiles = ((W + TW - 1) / TW) * ((H + TH - 1) / TH);
    dim3 grd(tiles, Cout, B);
    size_t shm = (size_t)(CinA + CinB) * 9 * sizeof(float);
    hipLaunchKernelGGL(conv3_k, grd, blk, shm, s, inA, CinA, inB, CinB, w, out, B, H, W, Cout);
}

static void launch_bn(float* z, float* stats, int B, int C, int HW, hipStream_t s) {
    hipLaunchKernelGGL(bn_stats_k, dim3(C), dim3(1024), 0, s, z, stats, B, C, HW);
    size_t total = (size_t)B * C * HW;
    int grid = (int)((total + 255) / 256);
    if (grid > 8192) grid = 8192;
    hipLaunchKernelGGL(bn_act_k, dim3(grid), dim3(256), 0, s, z, stats, C, HW, total);
}

extern "C" void kernel_launch(void* const* d_in, const int* in_sizes, int n_in,
                              void* d_out, int out_size, void* d_ws, size_t ws_size,
                              hipStream_t stream) {
    const float* feat0  = (const float*)d_in[0];   // (32,64,64,64)
    const float* feat1  = (const float*)d_in[1];   // (32,128,32,32)
    const float* bbox_s = (const float*)d_in[2];   // (1024,5)
    const float* bbox_m = (const float*)d_in[3];
    const float* bbox_l = (const float*)d_in[4];
    const float* d0_w1  = (const float*)d_in[5];   // (128,64,4,4)
    const float* d0_w2  = (const float*)d_in[6];   // (256,128,4,4)
    const float* d0_w3  = (const float*)d_in[7];   // (512,256,4,4)
    const float* d0_wo  = (const float*)d_in[8];   // (1,512,4,4)
    const float* d1_w1  = (const float*)d_in[9];   // (256,128,4,4)
    const float* d1_w2  = (const float*)d_in[10];  // (512,256,4,4)
    const float* d1_wo  = (const float*)d_in[11];  // (1,512,4,4)
    const float* lsb1_w = (const float*)d_in[12];  // (128,64,3,3)
    const float* lsb2_w = (const float*)d_in[13];  // (128,256,3,3)
    const float* lsb3_w = (const float*)d_in[14];  // (128,512,3,3)
    const float* last_w = (const float*)d_in[15];  // (1,128,4,4)
    float* out = (float*)d_out;

    const int B = 32, K = 1024;

    // workspace layout (floats)
    float* ws = (float*)d_ws;
    size_t o = 0;
    float* x1   = ws + o; o += (size_t)B * 128 * 32 * 32;  // 4194304
    float* x2   = ws + o; o += (size_t)B * 256 * 16 * 16;  // 2097152
    float* x3   = ws + o; o += (size_t)B * 512 * 8 * 8;    // 1048576
    float* y1   = ws + o; o += (size_t)B * 256 * 16 * 16;
    float* y2   = ws + o; o += (size_t)B * 512 * 8 * 8;
    float* a64  = ws + o; o += (size_t)B * 128 * 64 * 64;  // 16777216
    float* a32  = ws + o; o += (size_t)B * 128 * 32 * 32;
    float* a16  = ws + o; o += (size_t)B * 128 * 16 * 16;
    float* ssum = ws + o; o += (size_t)B * 128 * 8 * 8;    // 262144
    float* cnt  = ws + o; o += 64;
    float* stats = ws + o; o += 1024;

    // ---- branch 0 (from feat0) ----
    launch_down(feat0, d0_w1, x1, B, 64, 64, 64, 128, stream);
    launch_bn(x1, stats, B, 128, 32 * 32, stream);
    launch_down(x1, d0_w2, x2, B, 128, 32, 32, 256, stream);
    launch_bn(x2, stats, B, 256, 16 * 16, stream);
    launch_down(x2, d0_w3, x3, B, 256, 16, 16, 512, stream);
    launch_bn(x3, stats, B, 512, 8 * 8, stream);
    hipLaunchKernelGGL(logit_k, dim3(25, B), dim3(256), 0, stream, x3, d0_wo, out, 512, 50, 0);

    // ---- branch 1 (from feat1) ----
    launch_down(feat1, d1_w1, y1, B, 128, 32, 32, 256, stream);
    launch_bn(y1, stats, B, 256, 16 * 16, stream);
    launch_down(y1, d1_w2, y2, B, 256, 16, 16, 512, stream);
    launch_bn(y2, stats, B, 512, 8 * 8, stream);
    hipLaunchKernelGGL(logit_k, dim3(25, B), dim3(256), 0, stream, y2, d1_wo, out, 512, 50, 25);

    // ---- lsb branches ----
    launch_conv3(feat0, 64, nullptr, 0, lsb1_w, a64, B, 64, 64, 128, stream);
    launch_bn(a64, stats, B, 128, 64 * 64, stream);
    launch_conv3(x1, 128, feat1, 128, lsb2_w, a32, B, 32, 32, 128, stream);
    launch_bn(a32, stats, B, 128, 32 * 32, stream);
    launch_conv3(x2, 256, y1, 256, lsb3_w, a16, B, 16, 16, 128, stream);
    launch_bn(a16, stats, B, 128, 16 * 16, stream);

    // ---- ROI align + segment sum ----
    (void)hipMemsetAsync(ssum, 0, ((size_t)B * 128 * 64 + 64) * sizeof(float), stream);
    hipLaunchKernelGGL(roi_pool_k, dim3(K), dim3(256), 0, stream, a64, bbox_s, 128, 64, 64, ssum, cnt);
    hipLaunchKernelGGL(roi_pool_k, dim3(K), dim3(256), 0, stream, a32, bbox_m, 128, 32, 32, ssum, cnt);
    hipLaunchKernelGGL(roi_pool_k, dim3(K), dim3(256), 0, stream, a16, bbox_l, 128, 16, 16, ssum, cnt);

    // ---- final conv on pooled mean ----
    hipLaunchKernelGGL(final_k, dim3(25, B), dim3(256), 0, stream, ssum, cnt, last_w, out + 1600);
}

// Round 3
// 2913.893 us; speedup vs baseline: 7.1166x; 7.1166x over previous
//
#include <hip/hip_runtime.h>
#include <cstdint>
#include <cstddef>

#define LRELU(v) ((v) > 0.f ? (v) : 0.2f * (v))

// ---------------------------------------------------------------- implicit-GEMM conv
// C[M=Cout][N=B*Ho*Wo] = W[M][K=Cin*KH*KW] * im2col(X)[K][N]
// BM=BN=64, BK=16, 256 threads, 4x4 micro-tile per thread.
// Supports 2-tensor channel concat input (inA: CinA channels, inB: CinB).
// Requires: M%64==0, N%64==0, K%16==0 (true for every conv in this net).
template<int KHW, int KD, int STRIDE, int PAD>
__global__ __launch_bounds__(256) void conv_igemm_k(
    const float* __restrict__ inA, int CinA,
    const float* __restrict__ inB, int CinB,
    const float* __restrict__ w,
    float* __restrict__ out,
    int Hin, int Win, int Ho, int Wo, int Cout, int K)
{
    __shared__ float sA[16][64];
    __shared__ float sX[16][64];
    const int tid = threadIdx.x;
    const int m0 = blockIdx.y * 64;
    const int n0 = blockIdx.x * 64;
    const int HoWo = Ho * Wo;

    // staging thread mapping: 64 columns x 4-k quads
    const int lm = tid & 63;
    const int lk = (tid >> 6) * 4;

    // decode this thread's staged output-pixel once (constant over K loop)
    const int sn = n0 + lm;
    const int sb = sn / HoWo;
    const int srem = sn - sb * HoWo;
    const int sho = srem / Wo;
    const int swo = srem - sho * Wo;
    const int shi0 = sho * STRIDE - PAD;
    const int swi0 = swo * STRIDE - PAD;

    // compute thread mapping: 16x16 grid of 4x4 micro-tiles
    const int tm = tid >> 4;
    const int tn = tid & 15;

    float acc[4][4] = {};

    const float* wrow = w + (size_t)(m0 + lm) * K;

    for (int k0 = 0; k0 < K; k0 += 16) {
        // ---- stage weights: sA[k][m]
        float4 wv = *(const float4*)(wrow + k0 + lk);
        sA[lk + 0][lm] = wv.x;
        sA[lk + 1][lm] = wv.y;
        sA[lk + 2][lm] = wv.z;
        sA[lk + 3][lm] = wv.w;
        // ---- stage im2col: sX[k][n]
#pragma unroll
        for (int j = 0; j < 4; ++j) {
            int k = k0 + lk + j;
            int ci = k / KHW;
            int rs = k - ci * KHW;
            int r = rs / KD;
            int s = rs - r * KD;
            int hi = shi0 + r;
            int wi = swi0 + s;
            float v = 0.f;
            if ((unsigned)hi < (unsigned)Hin && (unsigned)wi < (unsigned)Win) {
                const float* src;
                if (ci < CinA) src = inA + ((size_t)sb * CinA + ci) * Hin * Win;
                else           src = inB + ((size_t)sb * CinB + (ci - CinA)) * Hin * Win;
                v = src[(size_t)hi * Win + wi];
            }
            sX[lk + j][lm] = v;
        }
        __syncthreads();
#pragma unroll
        for (int k = 0; k < 16; ++k) {
            float4 av = *(const float4*)&sA[k][tm * 4];
            float4 bv = *(const float4*)&sX[k][tn * 4];
            float a0 = av.x, a1 = av.y, a2 = av.z, a3 = av.w;
            float b0 = bv.x, b1 = bv.y, b2 = bv.z, b3 = bv.w;
            acc[0][0] = fmaf(a0, b0, acc[0][0]); acc[0][1] = fmaf(a0, b1, acc[0][1]);
            acc[0][2] = fmaf(a0, b2, acc[0][2]); acc[0][3] = fmaf(a0, b3, acc[0][3]);
            acc[1][0] = fmaf(a1, b0, acc[1][0]); acc[1][1] = fmaf(a1, b1, acc[1][1]);
            acc[1][2] = fmaf(a1, b2, acc[1][2]); acc[1][3] = fmaf(a1, b3, acc[1][3]);
            acc[2][0] = fmaf(a2, b0, acc[2][0]); acc[2][1] = fmaf(a2, b1, acc[2][1]);
            acc[2][2] = fmaf(a2, b2, acc[2][2]); acc[2][3] = fmaf(a2, b3, acc[2][3]);
            acc[3][0] = fmaf(a3, b0, acc[3][0]); acc[3][1] = fmaf(a3, b1, acc[3][1]);
            acc[3][2] = fmaf(a3, b2, acc[3][2]); acc[3][3] = fmaf(a3, b3, acc[3][3]);
        }
        __syncthreads();
    }

    // ---- epilogue: scatter 4x4 to NCHW
#pragma unroll
    for (int j = 0; j < 4; ++j) {
        int nn = n0 + tn * 4 + j;
        int b = nn / HoWo;
        int rem = nn - b * HoWo;
        float* op = out + ((size_t)b * Cout + m0 + tm * 4) * HoWo + rem;
#pragma unroll
        for (int i = 0; i < 4; ++i)
            op[(size_t)i * HoWo] = acc[i][j];
    }
}

// ---------------------------------------------------------------- BN stats: per-channel mean & rsqrt(var+eps)
__global__ void bn_stats_k(const float* __restrict__ z, float* __restrict__ stats,
                           int B, int C, int HW) {
    int c = blockIdx.x;
    float s = 0.f, s2 = 0.f;
    for (int b = 0; b < B; ++b) {
        const float* p = z + ((size_t)b * C + c) * HW;
        for (int i = threadIdx.x; i < HW; i += blockDim.x) {
            float v = p[i];
            s += v;
            s2 = fmaf(v, v, s2);
        }
    }
    __shared__ float sb1[16], sb2[16];
    for (int off = 32; off; off >>= 1) {
        s += __shfl_down(s, off, 64);
        s2 += __shfl_down(s2, off, 64);
    }
    int wid = threadIdx.x >> 6, lane = threadIdx.x & 63;
    if (lane == 0) { sb1[wid] = s; sb2[wid] = s2; }
    __syncthreads();
    if (threadIdx.x == 0) {
        int nwv = blockDim.x >> 6;
        s = 0.f; s2 = 0.f;
        for (int i = 0; i < nwv; ++i) { s += sb1[i]; s2 += sb2[i]; }
        float n = (float)B * (float)HW;
        float m = s / n;
        float var = s2 / n - m * m;
        stats[c] = m;
        stats[C + c] = rsqrtf(var + 1e-5f);
    }
}

// ---------------------------------------------------------------- BN apply + LReLU (in place)
__global__ void bn_act_k(float* __restrict__ z, const float* __restrict__ stats,
                         int C, int HW, size_t total) {
    size_t stride = (size_t)gridDim.x * blockDim.x;
    for (size_t i = (size_t)blockIdx.x * blockDim.x + threadIdx.x; i < total; i += stride) {
        int c = (int)((i / (size_t)HW) % (size_t)C);
        float v = (z[i] - stats[c]) * stats[C + c];
        z[i] = LRELU(v);
    }
}

// ---------------------------------------------------------------- logit conv: (B,Cin,8,8) -> 5x5 valid
__global__ void logit_k(const float* __restrict__ in, const float* __restrict__ w,
                        float* __restrict__ outp, int Cin, int outStrideB, int chOfs) {
    int p = blockIdx.x, b = blockIdx.y;
    int oy = p / 5, ox = p % 5;
    const float* inb = in + (size_t)b * Cin * 64;
    float acc = 0.f;
    int n = Cin * 16;
    for (int idx = threadIdx.x; idx < n; idx += blockDim.x) {
        int c = idx >> 4, t = idx & 15, r = t >> 2, s = t & 3;
        acc = fmaf(inb[(size_t)c * 64 + (oy + r) * 8 + (ox + s)], w[idx], acc);
    }
    __shared__ float sb[4];
    for (int off = 32; off; off >>= 1) acc += __shfl_down(acc, off, 64);
    int wid = threadIdx.x >> 6, lane = threadIdx.x & 63;
    if (lane == 0) sb[wid] = acc;
    __syncthreads();
    if (threadIdx.x == 0) {
        float t = sb[0] + sb[1] + sb[2] + sb[3];
        outp[(size_t)b * outStrideB + chOfs + p] = t;
    }
}

// ---------------------------------------------------------------- final conv: pooled (B,128,8,8) -> 5x5 valid
__global__ void final_k(const float* __restrict__ ssum, const float* __restrict__ cnt,
                        const float* __restrict__ w, float* __restrict__ outp) {
    int p = blockIdx.x, b = blockIdx.y;
    int oy = p / 5, ox = p % 5;
    float inv = 1.f / fmaxf(cnt[b], 1.f);
    const float* inb = ssum + (size_t)b * 128 * 64;
    float acc = 0.f;
    for (int idx = threadIdx.x; idx < 128 * 16; idx += blockDim.x) {
        int c = idx >> 4, t = idx & 15, r = t >> 2, s = t & 3;
        acc = fmaf(inb[(size_t)c * 64 + (oy + r) * 8 + (ox + s)], w[idx], acc);
    }
    __shared__ float sb[4];
    for (int off = 32; off; off >>= 1) acc += __shfl_down(acc, off, 64);
    int wid = threadIdx.x >> 6, lane = threadIdx.x & 63;
    if (lane == 0) sb[wid] = acc;
    __syncthreads();
    if (threadIdx.x == 0) {
        float t = sb[0] + sb[1] + sb[2] + sb[3];
        outp[(size_t)b * 25 + p] = t * inv;
    }
}

// ---------------------------------------------------------------- ROI align (out=8, n=2) fused with segment-sum
__global__ void roi_pool_k(const float* __restrict__ feat, const float* __restrict__ boxes,
                           int C, int H, int W,
                           float* __restrict__ ssum, float* __restrict__ cnt) {
    int k = blockIdx.x;
    const float* bx = boxes + (size_t)k * 5;
    __shared__ int sx0[16], sx1[16], sy0[16], sy1[16];
    __shared__ float slx[16], sly[16];
    __shared__ int sbid;
    int tid = threadIdx.x;
    if (tid < 16) {
        float x1 = bx[1], y1 = bx[2], x2 = bx[3], y2 = bx[4];
        float rw = fmaxf(x2 - x1, 1.0f), rh = fmaxf(y2 - y1, 1.0f);
        float g = ((float)tid + 0.5f) * 0.5f;
        float xs = fminf(fmaxf(x1 + g * (rw * 0.125f), 0.f), (float)(W - 1));
        float ys = fminf(fmaxf(y1 + g * (rh * 0.125f), 0.f), (float)(H - 1));
        int x0 = (int)floorf(xs), y0 = (int)floorf(ys);
        sx0[tid] = x0; sy0[tid] = y0;
        sx1[tid] = min(x0 + 1, W - 1);
        sy1[tid] = min(y0 + 1, H - 1);
        slx[tid] = xs - (float)x0;
        sly[tid] = ys - (float)y0;
        if (tid == 0) sbid = (int)bx[0];
    }
    __syncthreads();
    int bid = sbid;
    const float* fb = feat + (size_t)bid * C * H * W;
    int n = C * 64;
    for (int idx = tid; idx < n; idx += blockDim.x) {
        int c = idx >> 6, p = idx & 63, oy = p >> 3, ox = p & 7;
        const float* fc = fb + (size_t)c * H * W;
        float acc = 0.f;
#pragma unroll
        for (int iy = 0; iy < 2; ++iy) {
            int gy = oy * 2 + iy;
            int y0 = sy0[gy], y1 = sy1[gy];
            float ly = sly[gy];
#pragma unroll
            for (int ix = 0; ix < 2; ++ix) {
                int gx = ox * 2 + ix;
                int x0 = sx0[gx], x1 = sx1[gx];
                float lx = slx[gx];
                float v00 = fc[y0 * W + x0], v01 = fc[y0 * W + x1];
                float v10 = fc[y1 * W + x0], v11 = fc[y1 * W + x1];
                acc += (1.f - ly) * ((1.f - lx) * v00 + lx * v01) + ly * ((1.f - lx) * v10 + lx * v11);
            }
        }
        atomicAdd(&ssum[((size_t)bid * C + c) * 64 + p], acc * 0.25f);
    }
    if (tid == 0) atomicAdd(&cnt[bid], 1.0f);
}

// ---------------------------------------------------------------- host-side launch helpers
static void launch_down_ig(const float* in, const float* w, float* out,
                           int B, int Cin, int Hin, int Cout, hipStream_t s) {
    int Ho = Hin / 2;
    int N = B * Ho * Ho;
    int K = Cin * 16;
    dim3 grd(N / 64, Cout / 64);
    hipLaunchKernelGGL((conv_igemm_k<16, 4, 2, 1>), grd, dim3(256), 0, s,
                       in, Cin, (const float*)nullptr, 0, w, out,
                       Hin, Hin, Ho, Ho, Cout, K);
}

static void launch_conv3_ig(const float* inA, int CinA, const float* inB, int CinB,
                            const float* w, float* out,
                            int B, int H, int Cout, hipStream_t s) {
    int N = B * H * H;
    int K = (CinA + CinB) * 9;
    dim3 grd(N / 64, Cout / 64);
    hipLaunchKernelGGL((conv_igemm_k<9, 3, 1, 1>), grd, dim3(256), 0, s,
                       inA, CinA, inB, CinB, w, out,
                       H, H, H, H, Cout, K);
}

static void launch_bn(float* z, float* stats, int B, int C, int HW, hipStream_t s) {
    hipLaunchKernelGGL(bn_stats_k, dim3(C), dim3(1024), 0, s, z, stats, B, C, HW);
    size_t total = (size_t)B * C * HW;
    int grid = (int)((total + 255) / 256);
    if (grid > 8192) grid = 8192;
    hipLaunchKernelGGL(bn_act_k, dim3(grid), dim3(256), 0, s, z, stats, C, HW, total);
}

extern "C" void kernel_launch(void* const* d_in, const int* in_sizes, int n_in,
                              void* d_out, int out_size, void* d_ws, size_t ws_size,
                              hipStream_t stream) {
    const float* feat0  = (const float*)d_in[0];   // (32,64,64,64)
    const float* feat1  = (const float*)d_in[1];   // (32,128,32,32)
    const float* bbox_s = (const float*)d_in[2];   // (1024,5)
    const float* bbox_m = (const float*)d_in[3];
    const float* bbox_l = (const float*)d_in[4];
    const float* d0_w1  = (const float*)d_in[5];   // (128,64,4,4)
    const float* d0_w2  = (const float*)d_in[6];   // (256,128,4,4)
    const float* d0_w3  = (const float*)d_in[7];   // (512,256,4,4)
    const float* d0_wo  = (const float*)d_in[8];   // (1,512,4,4)
    const float* d1_w1  = (const float*)d_in[9];   // (256,128,4,4)
    const float* d1_w2  = (const float*)d_in[10];  // (512,256,4,4)
    const float* d1_wo  = (const float*)d_in[11];  // (1,512,4,4)
    const float* lsb1_w = (const float*)d_in[12];  // (128,64,3,3)
    const float* lsb2_w = (const float*)d_in[13];  // (128,256,3,3)
    const float* lsb3_w = (const float*)d_in[14];  // (128,512,3,3)
    const float* last_w = (const float*)d_in[15];  // (1,128,4,4)
    float* out = (float*)d_out;

    const int B = 32, K = 1024;

    // workspace layout (floats)
    float* ws = (float*)d_ws;
    size_t o = 0;
    float* x1   = ws + o; o += (size_t)B * 128 * 32 * 32;
    float* x2   = ws + o; o += (size_t)B * 256 * 16 * 16;
    float* x3   = ws + o; o += (size_t)B * 512 * 8 * 8;
    float* y1   = ws + o; o += (size_t)B * 256 * 16 * 16;
    float* y2   = ws + o; o += (size_t)B * 512 * 8 * 8;
    float* a64  = ws + o; o += (size_t)B * 128 * 64 * 64;
    float* a32  = ws + o; o += (size_t)B * 128 * 32 * 32;
    float* a16  = ws + o; o += (size_t)B * 128 * 16 * 16;
    float* ssum = ws + o; o += (size_t)B * 128 * 8 * 8;
    float* cnt  = ws + o; o += 64;
    float* stats = ws + o; o += 1024;

    // ---- branch 0 (from feat0) ----
    launch_down_ig(feat0, d0_w1, x1, B, 64, 64, 128, stream);
    launch_bn(x1, stats, B, 128, 32 * 32, stream);
    launch_down_ig(x1, d0_w2, x2, B, 128, 32, 256, stream);
    launch_bn(x2, stats, B, 256, 16 * 16, stream);
    launch_down_ig(x2, d0_w3, x3, B, 256, 16, 512, stream);
    launch_bn(x3, stats, B, 512, 8 * 8, stream);
    hipLaunchKernelGGL(logit_k, dim3(25, B), dim3(256), 0, stream, x3, d0_wo, out, 512, 50, 0);

    // ---- branch 1 (from feat1) ----
    launch_down_ig(feat1, d1_w1, y1, B, 128, 32, 256, stream);
    launch_bn(y1, stats, B, 256, 16 * 16, stream);
    launch_down_ig(y1, d1_w2, y2, B, 256, 16, 512, stream);
    launch_bn(y2, stats, B, 512, 8 * 8, stream);
    hipLaunchKernelGGL(logit_k, dim3(25, B), dim3(256), 0, stream, y2, d1_wo, out, 512, 50, 25);

    // ---- lsb branches ----
    launch_conv3_ig(feat0, 64, nullptr, 0, lsb1_w, a64, B, 64, 128, stream);
    launch_bn(a64, stats, B, 128, 64 * 64, stream);
    launch_conv3_ig(x1, 128, feat1, 128, lsb2_w, a32, B, 32, 128, stream);
    launch_bn(a32, stats, B, 128, 32 * 32, stream);
    launch_conv3_ig(x2, 256, y1, 256, lsb3_w, a16, B, 16, 128, stream);
    launch_bn(a16, stats, B, 128, 16 * 16, stream);

    // ---- ROI align + segment sum ----
    (void)hipMemsetAsync(ssum, 0, ((size_t)B * 128 * 64 + 64) * sizeof(float), stream);
    hipLaunchKernelGGL(roi_pool_k, dim3(K), dim3(256), 0, stream, a64, bbox_s, 128, 64, 64, ssum, cnt);
    hipLaunchKernelGGL(roi_pool_k, dim3(K), dim3(256), 0, stream, a32, bbox_m, 128, 32, 32, ssum, cnt);
    hipLaunchKernelGGL(roi_pool_k, dim3(K), dim3(256), 0, stream, a16, bbox_l, 128, 16, 16, ssum, cnt);

    // ---- final conv on pooled mean ----
    hipLaunchKernelGGL(final_k, dim3(25, B), dim3(256), 0, stream, ssum, cnt, last_w, out + 1600);
}

// Round 5
// 1306.049 us; speedup vs baseline: 15.8776x; 2.2311x over previous
//
#include <hip/hip_runtime.h>
#include <cstdint>
#include <cstddef>

typedef unsigned short u16;
typedef unsigned int uint;
typedef __attribute__((ext_vector_type(8))) short short8;
typedef __attribute__((ext_vector_type(4))) float f32x4;

#define LRELU(v) ((v) > 0.f ? (v) : 0.2f * (v))

__device__ inline float b2f(u16 u) { uint x = ((uint)u) << 16; return __builtin_bit_cast(float, x); }
__device__ inline u16 f2b(float f) {
    uint x = __builtin_bit_cast(uint, f);
    uint r = (x + 0x7FFFu + ((x >> 16) & 1u)) >> 16;
    return (u16)r;
}

// ---------------------------------------------------------------- fp32 -> bf16 convert
__global__ void cvt_k(const float* __restrict__ in, u16* __restrict__ out, size_t n4) {
    size_t stride = (size_t)gridDim.x * blockDim.x;
    for (size_t i = (size_t)blockIdx.x * blockDim.x + threadIdx.x; i < n4; i += stride) {
        float4 v = ((const float4*)in)[i];
        u16 o[4] = { f2b(v.x), f2b(v.y), f2b(v.z), f2b(v.w) };
        ((uint2*)out)[i] = *(const uint2*)o;
    }
}

// ---------------------------------------------------------------- weight pre-arrange to MFMA fragment order
// wf[mb][ks][mf(8)][lane(64)][j(8)] bf16, BM=128 fixed.
// k-order: k = rs*CIN + ci ; original OIHW index = (row*CIN + ci)*KHW + rs
__global__ void arrange_w_k(const float* __restrict__ w, u16* __restrict__ wf,
                            int CIN, int KHW, int K, int NK, int total) {
    for (int i = blockIdx.x * blockDim.x + threadIdx.x; i < total; i += gridDim.x * blockDim.x) {
        int j = i & 7;
        int t = i >> 3;
        int lane = t & 63; t >>= 6;
        int mf = t & 7; t >>= 3;
        int ks = t % NK;
        int mb = t / NK;
        int row = mb * 128 + mf * 16 + (lane & 15);
        int k = ks * 32 + ((lane >> 4) & 3) * 8 + j;
        int rs = k / CIN, ci = k % CIN;
        wf[i] = f2b(w[((size_t)row * CIN + ci) * KHW + rs]);
    }
}

// ---------------------------------------------------------------- MFMA implicit-GEMM conv (bf16 in, bf16 out, f32 acc)
// BM=128, BN=NFW*32, 256 threads (4 waves, 2x2 wave grid).
template<int CINA, int CINB, int H, int W, int STR, int PAD, int KD, int KHW, int NFW>
__global__ __launch_bounds__(256) void conv_mfma_k(
    const u16* __restrict__ inA, const u16* __restrict__ inB,
    const u16* __restrict__ wf, u16* __restrict__ zout, int Cout)
{
    constexpr int CIN = CINA + CINB;
    constexpr int K = CIN * KHW;
    constexpr int NK = K / 32;
    constexpr int HO = (H + 2 * PAD - KD) / STR + 1;
    constexpr int WO = HO;
    constexpr int HOWO = HO * WO;
    constexpr int BN = NFW * 32;
    constexpr int NFRAG = BN / 16;
    constexpr int HW = H * W;

    __shared__ uint4 sAq[512];          // 128x32 bf16 = 8KB
    __shared__ uint4 sBq[NFRAG * 64];   // 32xBN bf16

    const int tid = threadIdx.x;
    const int lane = tid & 63;
    const int wv = tid >> 6;
    const int m0 = blockIdx.y * 128;
    const int n0 = blockIdx.x * BN;

    // ---- B staging decode (per ff sub-fragment), constant over K loop
    const int kgrp = (tid >> 4) & 3;
    int shi0[NFW / 2 > 0 ? NFW / 2 : 1], swi0[NFW / 2 > 0 ? NFW / 2 : 1];
    const u16* bA[NFW / 2 > 0 ? NFW / 2 : 1];
    const u16* bB[NFW / 2 > 0 ? NFW / 2 : 1];
#pragma unroll
    for (int ff = 0; ff < NFW / 2; ++ff) {
        int nf = (tid >> 6) + 4 * ff;
        int col = nf * 16 + (tid & 15);
        int n = n0 + col;
        int sb = n / HOWO;
        int rem = n % HOWO;
        int sho = rem / WO;
        int swo = rem % WO;
        shi0[ff] = sho * STR - PAD;
        swi0[ff] = swo * STR - PAD;
        bA[ff] = inA + (size_t)sb * CINA * HW;
        bB[ff] = (CINB > 0 && inB) ? inB + (size_t)sb * CINB * HW : nullptr;
    }

    const uint4* wsq = (const uint4*)wf + (size_t)blockIdx.y * NK * 512;

    f32x4 acc[4][NFW];
#pragma unroll
    for (int i = 0; i < 4; ++i)
#pragma unroll
        for (int j = 0; j < NFW; ++j) acc[i][j] = (f32x4){0.f, 0.f, 0.f, 0.f};

    const int mf0 = (wv >> 1) * 4;
    const int nf0 = (wv & 1) * NFW;

    for (int ks = 0; ks < NK; ++ks) {
        // ---- stage A (linear copy of pre-arranged fragments)
        const uint4* wk = wsq + (size_t)ks * 512;
        sAq[tid] = wk[tid];
        sAq[tid + 256] = wk[tid + 256];
        // ---- stage B (im2col gather: per thread, per ff: 1 bounds check + 8 stride-HW loads)
        {
            int kb = ks * 32 + kgrp * 8;
            int rs = kb / CIN;
            int ci = kb % CIN;
            int r = rs / KD, s = rs - r * KD;
#pragma unroll
            for (int ff = 0; ff < NFW / 2; ++ff) {
                int hi = shi0[ff] + r, wi = swi0[ff] + s;
                bool ok = ((unsigned)hi < (unsigned)H) && ((unsigned)wi < (unsigned)W);
                const u16* p;
                if (CINB > 0 && ci >= CINA) p = bB[ff] + (size_t)(ci - CINA) * HW + hi * W + wi;
                else                        p = bA[ff] + (size_t)ci * HW + hi * W + wi;
                uint dw[4];
#pragma unroll
                for (int m = 0; m < 4; ++m) {
                    u16 u0 = 0, u1 = 0;
                    if (ok) { u0 = p[(2 * m) * HW]; u1 = p[(2 * m + 1) * HW]; }
                    dw[m] = (uint)u0 | ((uint)u1 << 16);
                }
                int nf = (tid >> 6) + 4 * ff;
                sBq[nf * 64 + lane] = make_uint4(dw[0], dw[1], dw[2], dw[3]);
            }
        }
        __syncthreads();
        // ---- compute
        short8 bfr[NFW];
#pragma unroll
        for (int j = 0; j < NFW; ++j) bfr[j] = *(const short8*)&sBq[(nf0 + j) * 64 + lane];
#pragma unroll
        for (int i = 0; i < 4; ++i) {
            short8 af = *(const short8*)&sAq[(mf0 + i) * 64 + lane];
#pragma unroll
            for (int j = 0; j < NFW; ++j)
                acc[i][j] = __builtin_amdgcn_mfma_f32_16x16x32_bf16(af, bfr[j], acc[i][j], 0, 0, 0);
        }
        __syncthreads();
    }

    // ---- epilogue: D row=(lane>>4)*4+r, col=lane&15 ; write bf16
#pragma unroll
    for (int j = 0; j < NFW; ++j) {
        int col = n0 + (nf0 + j) * 16 + (lane & 15);
        int b = col / HOWO;
        int rem = col % HOWO;
#pragma unroll
        for (int i = 0; i < 4; ++i) {
            int rowb = m0 + (mf0 + i) * 16 + (lane >> 4) * 4;
            u16* op = zout + ((size_t)b * Cout + rowb) * HOWO + rem;
#pragma unroll
            for (int r = 0; r < 4; ++r)
                op[(size_t)r * HOWO] = f2b(acc[i][j][r]);
        }
    }
}

// ---------------------------------------------------------------- BN stats on bf16 (mean, rsqrt(var+eps))
__global__ void bn_stats_b_k(const u16* __restrict__ z, float* __restrict__ stats,
                             int B, int C, int HW) {
    int c = blockIdx.x;
    float s = 0.f, s2 = 0.f;
    for (int b = 0; b < B; ++b) {
        const u16* p = z + ((size_t)b * C + c) * HW;
        for (int i = threadIdx.x * 8; i < HW; i += blockDim.x * 8) {
            uint4 v = *(const uint4*)(p + i);
            const u16* e = (const u16*)&v;
#pragma unroll
            for (int j = 0; j < 8; ++j) { float f = b2f(e[j]); s += f; s2 = fmaf(f, f, s2); }
        }
    }
    __shared__ float sb1[8], sb2[8];
    for (int off = 32; off; off >>= 1) {
        s += __shfl_down(s, off, 64);
        s2 += __shfl_down(s2, off, 64);
    }
    int wid = threadIdx.x >> 6, ln = threadIdx.x & 63;
    if (ln == 0) { sb1[wid] = s; sb2[wid] = s2; }
    __syncthreads();
    if (threadIdx.x == 0) {
        int nwv = blockDim.x >> 6;
        s = 0.f; s2 = 0.f;
        for (int i = 0; i < nwv; ++i) { s += sb1[i]; s2 += sb2[i]; }
        float n = (float)B * (float)HW;
        float m = s / n;
        float var = fmaxf(s2 / n - m * m, 0.f);
        stats[c] = m;
        stats[C + c] = rsqrtf(var + 1e-5f);
    }
}

// ---------------------------------------------------------------- BN apply + LReLU in place (bf16)
__global__ void bn_act_b_k(u16* __restrict__ z, const float* __restrict__ stats,
                           int C, int HW, size_t total8) {
    size_t stride = (size_t)gridDim.x * blockDim.x;
    for (size_t i = (size_t)blockIdx.x * blockDim.x + threadIdx.x; i < total8; i += stride) {
        size_t e0 = i * 8;
        int c = (int)((e0 / (size_t)HW) % (size_t)C);
        float m = stats[c], rs = stats[C + c];
        uint4 v = ((const uint4*)z)[i];
        u16* e = (u16*)&v;
        u16 o[8];
#pragma unroll
        for (int j = 0; j < 8; ++j) {
            float f = (b2f(e[j]) - m) * rs;
            o[j] = f2b(LRELU(f));
        }
        ((uint4*)z)[i] = *(const uint4*)o;
    }
}

// ---------------------------------------------------------------- logit conv: bf16 (B,Cin,8,8) -> 5x5 valid
__global__ void logit_k(const u16* __restrict__ in, const float* __restrict__ w,
                        float* __restrict__ outp, int Cin, int outStrideB, int chOfs) {
    int p = blockIdx.x, b = blockIdx.y;
    int oy = p / 5, ox = p % 5;
    const u16* inb = in + (size_t)b * Cin * 64;
    float acc = 0.f;
    int n = Cin * 16;
    for (int idx = threadIdx.x; idx < n; idx += blockDim.x) {
        int c = idx >> 4, t = idx & 15, r = t >> 2, s = t & 3;
        acc = fmaf(b2f(inb[(size_t)c * 64 + (oy + r) * 8 + (ox + s)]), w[idx], acc);
    }
    __shared__ float sb[4];
    for (int off = 32; off; off >>= 1) acc += __shfl_down(acc, off, 64);
    int wid = threadIdx.x >> 6, ln = threadIdx.x & 63;
    if (ln == 0) sb[wid] = acc;
    __syncthreads();
    if (threadIdx.x == 0) {
        float t = sb[0] + sb[1] + sb[2] + sb[3];
        outp[(size_t)b * outStrideB + chOfs + p] = t;
    }
}

// ---------------------------------------------------------------- final conv on pooled mean (fp32)
__global__ void final_k(const float* __restrict__ ssum, const float* __restrict__ cnt,
                        const float* __restrict__ w, float* __restrict__ outp) {
    int p = blockIdx.x, b = blockIdx.y;
    int oy = p / 5, ox = p % 5;
    float inv = 1.f / fmaxf(cnt[b], 1.f);
    const float* inb = ssum + (size_t)b * 128 * 64;
    float acc = 0.f;
    for (int idx = threadIdx.x; idx < 128 * 16; idx += blockDim.x) {
        int c = idx >> 4, t = idx & 15, r = t >> 2, s = t & 3;
        acc = fmaf(inb[(size_t)c * 64 + (oy + r) * 8 + (ox + s)], w[idx], acc);
    }
    __shared__ float sb[4];
    for (int off = 32; off; off >>= 1) acc += __shfl_down(acc, off, 64);
    int wid = threadIdx.x >> 6, ln = threadIdx.x & 63;
    if (ln == 0) sb[wid] = acc;
    __syncthreads();
    if (threadIdx.x == 0) {
        float t = sb[0] + sb[1] + sb[2] + sb[3];
        outp[(size_t)b * 25 + p] = t * inv;
    }
}

// ---------------------------------------------------------------- ROI align (out=8, n=2) on bf16 + segment-sum
__global__ void roi_pool_k(const u16* __restrict__ feat, const float* __restrict__ boxes,
                           int C, int H, int W,
                           float* __restrict__ ssum, float* __restrict__ cnt) {
    int k = blockIdx.x;
    const float* bx = boxes + (size_t)k * 5;
    __shared__ int sx0[16], sx1[16], sy0[16], sy1[16];
    __shared__ float slx[16], sly[16];
    __shared__ int sbid;
    int tid = threadIdx.x;
    if (tid < 16) {
        float x1 = bx[1], y1 = bx[2], x2 = bx[3], y2 = bx[4];
        float rw = fmaxf(x2 - x1, 1.0f), rh = fmaxf(y2 - y1, 1.0f);
        float g = ((float)tid + 0.5f) * 0.5f;
        float xs = fminf(fmaxf(x1 + g * (rw * 0.125f), 0.f), (float)(W - 1));
        float ys = fminf(fmaxf(y1 + g * (rh * 0.125f), 0.f), (float)(H - 1));
        int x0 = (int)floorf(xs), y0 = (int)floorf(ys);
        sx0[tid] = x0; sy0[tid] = y0;
        sx1[tid] = min(x0 + 1, W - 1);
        sy1[tid] = min(y0 + 1, H - 1);
        slx[tid] = xs - (float)x0;
        sly[tid] = ys - (float)y0;
        if (tid == 0) sbid = (int)bx[0];
    }
    __syncthreads();
    int bid = sbid;
    const u16* fb = feat + (size_t)bid * C * H * W;
    int n = C * 64;
    for (int idx = tid; idx < n; idx += blockDim.x) {
        int c = idx >> 6, p = idx & 63, oy = p >> 3, ox = p & 7;
        const u16* fc = fb + (size_t)c * H * W;
        float acc = 0.f;
#pragma unroll
        for (int iy = 0; iy < 2; ++iy) {
            int gy = oy * 2 + iy;
            int y0 = sy0[gy], y1 = sy1[gy];
            float ly = sly[gy];
#pragma unroll
            for (int ix = 0; ix < 2; ++ix) {
                int gx = ox * 2 + ix;
                int x0 = sx0[gx], x1 = sx1[gx];
                float lx = slx[gx];
                float v00 = b2f(fc[y0 * W + x0]), v01 = b2f(fc[y0 * W + x1]);
                float v10 = b2f(fc[y1 * W + x0]), v11 = b2f(fc[y1 * W + x1]);
                acc += (1.f - ly) * ((1.f - lx) * v00 + lx * v01) + ly * ((1.f - lx) * v10 + lx * v11);
            }
        }
        atomicAdd(&ssum[((size_t)bid * C + c) * 64 + p], acc * 0.25f);
    }
    if (tid == 0) atomicAdd(&cnt[bid], 1.0f);
}

// ---------------------------------------------------------------- helpers
static void launch_bn(u16* z, float* stats, int B, int C, int HW, hipStream_t s) {
    hipLaunchKernelGGL(bn_stats_b_k, dim3(C), dim3(256), 0, s, z, stats, B, C, HW);
    size_t total8 = (size_t)B * C * HW / 8;
    int grid = (int)((total8 + 255) / 256);
    if (grid > 4096) grid = 4096;
    hipLaunchKernelGGL(bn_act_b_k, dim3(grid), dim3(256), 0, s, z, stats, C, HW, total8);
}

static void launch_arrange(const float* w, u16* wf, int Cout, int CIN, int KHW, hipStream_t s) {
    int K = CIN * KHW;
    int NK = K / 32;
    int total = Cout * K;
    int grid = (total + 255) / 256;
    if (grid > 2048) grid = 2048;
    hipLaunchKernelGGL(arrange_w_k, dim3(grid), dim3(256), 0, s, w, wf, CIN, KHW, K, NK, total);
}

extern "C" void kernel_launch(void* const* d_in, const int* in_sizes, int n_in,
                              void* d_out, int out_size, void* d_ws, size_t ws_size,
                              hipStream_t stream) {
    const float* feat0  = (const float*)d_in[0];   // (32,64,64,64)
    const float* feat1  = (const float*)d_in[1];   // (32,128,32,32)
    const float* bbox_s = (const float*)d_in[2];
    const float* bbox_m = (const float*)d_in[3];
    const float* bbox_l = (const float*)d_in[4];
    const float* d0_w1  = (const float*)d_in[5];   // (128,64,4,4)
    const float* d0_w2  = (const float*)d_in[6];   // (256,128,4,4)
    const float* d0_w3  = (const float*)d_in[7];   // (512,256,4,4)
    const float* d0_wo  = (const float*)d_in[8];
    const float* d1_w1  = (const float*)d_in[9];   // (256,128,4,4)
    const float* d1_w2  = (const float*)d_in[10];  // (512,256,4,4)
    const float* d1_wo  = (const float*)d_in[11];
    const float* lsb1_w = (const float*)d_in[12];  // (128,64,3,3)
    const float* lsb2_w = (const float*)d_in[13];  // (128,256,3,3)
    const float* lsb3_w = (const float*)d_in[14];  // (128,512,3,3)
    const float* last_w = (const float*)d_in[15];
    float* out = (float*)d_out;

    const int B = 32, K = 1024;

    // ---- workspace layout (bytes, 256-aligned chunks)
    char* wsb = (char*)d_ws;
    auto alloc = [&](size_t bytes) -> void* {
        void* p = (void*)wsb;
        wsb += (bytes + 255) & ~(size_t)255;
        return p;
    };
    u16* f0b  = (u16*)alloc((size_t)B * 64 * 64 * 64 * 2);
    u16* f1b  = (u16*)alloc((size_t)B * 128 * 32 * 32 * 2);
    u16* x1b  = (u16*)alloc((size_t)B * 128 * 32 * 32 * 2);
    u16* x2b  = (u16*)alloc((size_t)B * 256 * 16 * 16 * 2);
    u16* x3b  = (u16*)alloc((size_t)B * 512 * 8 * 8 * 2);
    u16* y1b  = (u16*)alloc((size_t)B * 256 * 16 * 16 * 2);
    u16* y2b  = (u16*)alloc((size_t)B * 512 * 8 * 8 * 2);
    u16* a64b = (u16*)alloc((size_t)B * 128 * 64 * 64 * 2);
    u16* a32b = (u16*)alloc((size_t)B * 128 * 32 * 32 * 2);
    u16* a16b = (u16*)alloc((size_t)B * 128 * 16 * 16 * 2);
    u16* wf_d0w1 = (u16*)alloc((size_t)128 * 1024 * 2);
    u16* wf_d0w2 = (u16*)alloc((size_t)256 * 2048 * 2);
    u16* wf_d0w3 = (u16*)alloc((size_t)512 * 4096 * 2);
    u16* wf_d1w1 = (u16*)alloc((size_t)256 * 2048 * 2);
    u16* wf_d1w2 = (u16*)alloc((size_t)512 * 4096 * 2);
    u16* wf_l1   = (u16*)alloc((size_t)128 * 576 * 2);
    u16* wf_l2   = (u16*)alloc((size_t)128 * 2304 * 2);
    u16* wf_l3   = (u16*)alloc((size_t)128 * 4608 * 2);
    float* ssum  = (float*)alloc((size_t)B * 128 * 64 * 4);
    float* cnt   = (float*)alloc(64 * 4);
    float* stats = (float*)alloc(1024 * 4);

    // ---- input converts
    hipLaunchKernelGGL(cvt_k, dim3(2048), dim3(256), 0, stream, feat0, f0b, (size_t)B * 64 * 64 * 64 / 4);
    hipLaunchKernelGGL(cvt_k, dim3(2048), dim3(256), 0, stream, feat1, f1b, (size_t)B * 128 * 32 * 32 / 4);

    // ---- weight pre-arrangement
    launch_arrange(d0_w1, wf_d0w1, 128, 64, 16, stream);
    launch_arrange(d0_w2, wf_d0w2, 256, 128, 16, stream);
    launch_arrange(d0_w3, wf_d0w3, 512, 256, 16, stream);
    launch_arrange(d1_w1, wf_d1w1, 256, 128, 16, stream);
    launch_arrange(d1_w2, wf_d1w2, 512, 256, 16, stream);
    launch_arrange(lsb1_w, wf_l1, 128, 64, 9, stream);
    launch_arrange(lsb2_w, wf_l2, 128, 256, 9, stream);
    launch_arrange(lsb3_w, wf_l3, 128, 512, 9, stream);

    // ---- branch 0
    hipLaunchKernelGGL((conv_mfma_k<64, 0, 64, 64, 2, 1, 4, 16, 4>), dim3(256, 1), dim3(256), 0, stream,
                       f0b, (const u16*)nullptr, wf_d0w1, x1b, 128);
    launch_bn(x1b, stats, B, 128, 32 * 32, stream);
    hipLaunchKernelGGL((conv_mfma_k<128, 0, 32, 32, 2, 1, 4, 16, 2>), dim3(128, 2), dim3(256), 0, stream,
                       x1b, (const u16*)nullptr, wf_d0w2, x2b, 256);
    launch_bn(x2b, stats, B, 256, 16 * 16, stream);
    hipLaunchKernelGGL((conv_mfma_k<256, 0, 16, 16, 2, 1, 4, 16, 2>), dim3(32, 4), dim3(256), 0, stream,
                       x2b, (const u16*)nullptr, wf_d0w3, x3b, 512);
    launch_bn(x3b, stats, B, 512, 8 * 8, stream);
    hipLaunchKernelGGL(logit_k, dim3(25, B), dim3(256), 0, stream, x3b, d0_wo, out, 512, 50, 0);

    // ---- branch 1
    hipLaunchKernelGGL((conv_mfma_k<128, 0, 32, 32, 2, 1, 4, 16, 2>), dim3(128, 2), dim3(256), 0, stream,
                       f1b, (const u16*)nullptr, wf_d1w1, y1b, 256);
    launch_bn(y1b, stats, B, 256, 16 * 16, stream);
    hipLaunchKernelGGL((conv_mfma_k<256, 0, 16, 16, 2, 1, 4, 16, 2>), dim3(32, 4), dim3(256), 0, stream,
                       y1b, (const u16*)nullptr, wf_d1w2, y2b, 512);
    launch_bn(y2b, stats, B, 512, 8 * 8, stream);
    hipLaunchKernelGGL(logit_k, dim3(25, B), dim3(256), 0, stream, y2b, d1_wo, out, 512, 50, 25);

    // ---- lsb branches
    hipLaunchKernelGGL((conv_mfma_k<64, 0, 64, 64, 1, 1, 3, 9, 4>), dim3(1024, 1), dim3(256), 0, stream,
                       f0b, (const u16*)nullptr, wf_l1, a64b, 128);
    launch_bn(a64b, stats, B, 128, 64 * 64, stream);
    hipLaunchKernelGGL((conv_mfma_k<128, 128, 32, 32, 1, 1, 3, 9, 4>), dim3(256, 1), dim3(256), 0, stream,
                       x1b, f1b, wf_l2, a32b, 128);
    launch_bn(a32b, stats, B, 128, 32 * 32, stream);
    // Cout=128 here -> grid.y MUST be 1 (was 2: OOB reads past wf_l3 + OOB/racy writes past a16b)
    hipLaunchKernelGGL((conv_mfma_k<256, 256, 16, 16, 1, 1, 3, 9, 2>), dim3(128, 1), dim3(256), 0, stream,
                       x2b, y1b, wf_l3, a16b, 128);
    launch_bn(a16b, stats, B, 128, 16 * 16, stream);

    // ---- ROI align + segment sum
    (void)hipMemsetAsync(ssum, 0, ((size_t)B * 128 * 64 + 64) * sizeof(float), stream);
    hipLaunchKernelGGL(roi_pool_k, dim3(K), dim3(256), 0, stream, a64b, bbox_s, 128, 64, 64, ssum, cnt);
    hipLaunchKernelGGL(roi_pool_k, dim3(K), dim3(256), 0, stream, a32b, bbox_m, 128, 32, 32, ssum, cnt);
    hipLaunchKernelGGL(roi_pool_k, dim3(K), dim3(256), 0, stream, a16b, bbox_l, 128, 16, 16, ssum, cnt);

    // ---- final conv
    hipLaunchKernelGGL(final_k, dim3(25, B), dim3(256), 0, stream, ssum, cnt, last_w, out + 1600);
}